// Round 1
// 349.383 us; speedup vs baseline: 1.2315x; 1.2315x over previous
//
#include <hip/hip_runtime.h>
#include <cstdint>
#include <cstddef>

typedef __bf16 bf16_t;
typedef __attribute__((ext_vector_type(4))) __bf16 bf16x4_t;
typedef __attribute__((ext_vector_type(8))) __bf16 bf16x8_t;
typedef __attribute__((ext_vector_type(4))) float f32x4_t;

#define T_TOK   4096
#define IN_DIM  4096
#define OUT_DIM 4096
#define K2      320    // 256 hk cols | 8 w cols | 1 shared_b col | 55 zero pad (5x BK=64 tiles)
#define KSPLIT  8      // gate split-K (512 wide)
#define HSPLIT  8      // svh-gemm split-K (K=512 each) -> 512 blocks
#define NT_TILES 69    // 64 main K-tiles (4096/64) + 5 tail tiles (320/64)

#define XSZ ((size_t)T_TOK * IN_DIM)
#define WSZ ((size_t)OUT_DIM * IN_DIM)
#define VSZ ((size_t)256 * IN_DIM)
#define NCAST ((XSZ + WSZ + VSZ) / 1024)     // 33792 cast blocks
#define NGATE (64 * KSPLIT)                  // 512 gate blocks
#define NB2T  OUT_DIM                        // 4096 b2t blocks

__device__ __forceinline__ void gload_lds16(const bf16_t* g, bf16_t* l) {
  __builtin_amdgcn_global_load_lds(
      (__attribute__((address_space(1))) void*)(g),
      (__attribute__((address_space(3))) void*)(l), 16, 0, 0);
}

// ===== K1: uber-kernel — gate partials | B2t build | fp32->bf16 casts ======
// block order: gate (long, LDS-bound) first so it overlaps the cast sea.
__global__ __launch_bounds__(256) void k1_prep(const float* __restrict__ x,
                                               const float* __restrict__ gw,
                                               const float* __restrict__ sw,
                                               const float* __restrict__ svh,
                                               const float* __restrict__ u,
                                               const float* __restrict__ eb,
                                               const float* __restrict__ sb,
                                               bf16_t* __restrict__ Xbf,
                                               bf16_t* __restrict__ Wbf,
                                               bf16_t* __restrict__ Vbf,
                                               bf16_t* __restrict__ B2t,
                                               float* __restrict__ part) {
  __shared__ __align__(16) float GateLds[64 * 68 * 2];  // 34.8 KB (gate only)
  const int bid = blockIdx.x;
  const int tid = threadIdx.x;

  if (bid < NGATE) {
    // ---- fp32 gate matmul partials (router precision) ----
    float* Xs = GateLds;            // [kk][t] stride 68
    float* Gs = GateLds + 64 * 68;  // [kk][r]
    const int tbase = (bid & 63) * 64;
    const int kbase = (bid >> 6) * (IN_DIM / KSPLIT);
    const int tg = tid & 15;
    const int rg = tid >> 4;
    float acc[4][4] = {{0.f}};

    for (int cc = 0; cc < (IN_DIM / KSPLIT) / 64; ++cc) {
      const int kc = kbase + cc * 64;
      __syncthreads();
#pragma unroll
      for (int j = 0; j < 4; ++j) {
        const int f = tid * 16 + j * 4;
        const int tt = f >> 6, k4 = f & 63;
        float4 xv = *(const float4*)&x[(size_t)(tbase + tt) * IN_DIM + kc + k4];
        Xs[(k4 + 0) * 68 + tt] = xv.x; Xs[(k4 + 1) * 68 + tt] = xv.y;
        Xs[(k4 + 2) * 68 + tt] = xv.z; Xs[(k4 + 3) * 68 + tt] = xv.w;
        float4 gv = *(const float4*)&gw[(size_t)tt * IN_DIM + kc + k4];
        Gs[(k4 + 0) * 68 + tt] = gv.x; Gs[(k4 + 1) * 68 + tt] = gv.y;
        Gs[(k4 + 2) * 68 + tt] = gv.z; Gs[(k4 + 3) * 68 + tt] = gv.w;
      }
      __syncthreads();
#pragma unroll 4
      for (int kk = 0; kk < 64; ++kk) {
        float4 xv = *(const float4*)&Xs[kk * 68 + tg * 4];
        float4 gv = *(const float4*)&Gs[kk * 68 + rg * 4];
        float xa[4] = {xv.x, xv.y, xv.z, xv.w};
        float ga[4] = {gv.x, gv.y, gv.z, gv.w};
#pragma unroll
        for (int i = 0; i < 4; ++i)
#pragma unroll
          for (int j = 0; j < 4; ++j) acc[i][j] = fmaf(xa[i], ga[j], acc[i][j]);
      }
    }
    const int ks = bid >> 6;
#pragma unroll
    for (int i = 0; i < 4; ++i) {
      float4 o4 = make_float4(acc[i][0], acc[i][1], acc[i][2], acc[i][3]);
      *(float4*)&part[((size_t)ks * T_TOK + tbase + tg * 4 + i) * 64 + rg * 4] = o4;
    }
  } else if (bid < NGATE + NB2T) {
    // ---- B2t[o][c] = u[e][o][k] | eb[e][o] | sb[o] | 0 ----
    const int o = bid - NGATE;
    for (int c = tid; c < K2; c += 256) {
      float v;
      if (c < 256)       v = u[((size_t)(c >> 5) * OUT_DIM + o) * 32 + (c & 31)];
      else if (c < 264)  v = eb[(size_t)(c - 256) * OUT_DIM + o];
      else if (c == 264) v = sb[o];
      else               v = 0.f;
      B2t[(size_t)o * K2 + c] = (__bf16)v;
    }
  } else {
    // ---- casts: x->Xbf, sw->Wbf, svh->Vbf ----
    size_t idx = ((size_t)(bid - NGATE - NB2T) * 256 + tid) * 4;
    const float* src; bf16_t* dst; size_t i;
    if (idx < XSZ)            { src = x;   dst = Xbf; i = idx; }
    else if (idx < XSZ + WSZ) { src = sw;  dst = Wbf; i = idx - XSZ; }
    else                      { src = svh; dst = Vbf; i = idx - XSZ - WSZ; }
    float4 v = *(const float4*)(src + i);
    bf16x4_t o;
    o[0] = (__bf16)v.x; o[1] = (__bf16)v.y; o[2] = (__bf16)v.z; o[3] = (__bf16)v.w;
    *(bf16x4_t*)(dst + i) = o;
  }
}

// ===== K2: svh split-K GEMM: hkp[s][t][n] = sum_{k in s} Xbf[t,k]Vbf[n,k] ===
// grid (2, 32, HSPLIT) = 512 blocks (2/CU), 128x128 tile, K chunk = 512.
__global__ __launch_bounds__(256) void svh_gemm(const bf16_t* __restrict__ X,
                                                const bf16_t* __restrict__ V,
                                                float* __restrict__ hkp) {
  __shared__ __align__(16) bf16_t As[128 * 32];
  __shared__ __align__(16) bf16_t Bs[128 * 32];
  const int tid = threadIdx.x;
  const int wave = tid >> 6, lane = tid & 63;
  const int mBase = blockIdx.y * 128, nBase = blockIdx.x * 128;
  const int koff = blockIdx.z * (IN_DIM / HSPLIT);
  const int wm = wave >> 1, wn = wave & 1;
  const int lr = lane & 15, lk = (lane >> 4) * 8;
  const int arow = lane >> 2, acol = (lane & 3) * 8;

  f32x4_t acc[4][4];
#pragma unroll
  for (int i = 0; i < 4; ++i)
#pragma unroll
    for (int j = 0; j < 4; ++j) { f32x4_t z = {0.f, 0.f, 0.f, 0.f}; acc[i][j] = z; }

  const bf16_t* gA = X + (size_t)(mBase + wave * 32 + arow) * IN_DIM + koff + acol;
  const bf16_t* gB = V + (size_t)(nBase + wave * 32 + arow) * IN_DIM + koff + acol;
  bf16_t* lA = &As[(wave * 32) * 32];
  bf16_t* lB = &Bs[(wave * 32) * 32];

  for (int k0 = 0; k0 < IN_DIM / HSPLIT; k0 += 32) {
    gload_lds16(gA + k0, lA);
    gload_lds16(gA + k0 + (size_t)16 * IN_DIM, lA + 16 * 32);
    gload_lds16(gB + k0, lB);
    gload_lds16(gB + k0 + (size_t)16 * IN_DIM, lB + 16 * 32);
    __syncthreads();
    bf16x8_t a[4], b[4];
#pragma unroll
    for (int mi = 0; mi < 4; ++mi)
      a[mi] = *(const bf16x8_t*)&As[(wm * 64 + mi * 16 + lr) * 32 + lk];
#pragma unroll
    for (int ni = 0; ni < 4; ++ni)
      b[ni] = *(const bf16x8_t*)&Bs[(wn * 64 + ni * 16 + lr) * 32 + lk];
#pragma unroll
    for (int mi = 0; mi < 4; ++mi)
#pragma unroll
      for (int ni = 0; ni < 4; ++ni)
        acc[mi][ni] = __builtin_amdgcn_mfma_f32_16x16x32_bf16(a[mi], b[ni], acc[mi][ni], 0, 0, 0);
    __syncthreads();
  }

  const int row0 = (lane >> 4) * 4;
  float* hs = hkp + (size_t)blockIdx.z * T_TOK * 256;
#pragma unroll
  for (int mi = 0; mi < 4; ++mi) {
    const int m = mBase + wm * 64 + mi * 16 + row0;
#pragma unroll
    for (int ni = 0; ni < 4; ++ni) {
      const int n = nBase + wn * 64 + ni * 16 + lr;
      f32x4_t v = acc[mi][ni];
#pragma unroll
      for (int r = 0; r < 4; ++r) hs[(size_t)(m + r) * 256 + n] = v[r];
    }
  }
}

// ===== K3: router + A2, wide (256 blocks x 16 tokens, cooperative) ==========
// A2[t][c] = (sum_s hkp[s][t][c]) * w_{t,c>>5} | w_{t,0..7} | 1.0 | 0pad
__global__ __launch_bounds__(256) void router_a2(const float* __restrict__ part,
                                                 const float* __restrict__ hkp,
                                                 bf16_t* __restrict__ A2) {
  __shared__ float pl[16 * 16];   // [token][rquad] partial sum-of-squares
  __shared__ float wls[16 * 8];   // [token][expert] routed weights
  const int tid = threadIdx.x;
  const int tbase = blockIdx.x * 16;

  // phase A: thread (tt, rq) sums 4 r-values over KSPLIT splits, squares
  {
    const int tt = tid >> 4, rq = tid & 15;
    const int t = tbase + tt;
    float4 s = make_float4(0.f, 0.f, 0.f, 0.f);
#pragma unroll
    for (int ks = 0; ks < KSPLIT; ++ks) {
      float4 p = *(const float4*)&part[((size_t)ks * T_TOK + t) * 64 + rq * 4];
      s.x += p.x; s.y += p.y; s.z += p.z; s.w += p.w;
    }
    pl[tt * 16 + rq] = s.x * s.x + s.y * s.y + s.z * s.z + s.w * s.w;
  }
  __syncthreads();
  if (tid < 16) {
    const int tt = tid;
    float rl[8];
#pragma unroll
    for (int e = 0; e < 8; ++e)
      rl[e] = sqrtf(pl[tt * 16 + e * 2] + pl[tt * 16 + e * 2 + 1]);
    int e1 = 0; float v1 = rl[0];
#pragma unroll
    for (int e = 1; e < 8; ++e) if (rl[e] > v1) { v1 = rl[e]; e1 = e; }
    int e2 = -1; float v2 = -1e30f;
#pragma unroll
    for (int e = 0; e < 8; ++e) if (e != e1 && rl[e] > v2) { v2 = rl[e]; e2 = e; }
    float w1 = 1.f / (1.f + expf(v2 - v1));
#pragma unroll
    for (int e = 0; e < 8; ++e) wls[tt * 8 + e] = 0.f;
    wls[tt * 8 + e1] = w1; wls[tt * 8 + e2] = 1.f - w1;
  }
  __syncthreads();
  // phase B: A2 rows for 16 tokens
  for (int tt = 0; tt < 16; ++tt) {
    const int t = tbase + tt;
    for (int c = tid; c < K2; c += 256) {
      float v;
      if (c < 256) {
        float s = 0.f;
#pragma unroll
        for (int ks = 0; ks < HSPLIT; ++ks)
          s += hkp[((size_t)ks * T_TOK + t) * 256 + c];
        v = s * wls[tt * 8 + (c >> 5)];
      } else if (c < 264) v = wls[tt * 8 + (c - 256)];
      else if (c == 264)  v = 1.0f;
      else                v = 0.f;
      A2[(size_t)t * K2 + c] = (__bf16)v;
    }
  }
}

// ===== K4: fused GEMM: out = Xbf.Wbf^T (K=4096) + A2.B2t^T (K=320) =========
// 256x256 tile, BK=64, 8 waves (2Mx4N, 128x64 out each), double-buffered
// 128 KiB LDS, raw s_barrier + counted vmcnt(8) (loads stay in flight across
// barriers), XOR bank-swizzle (pre-swizzled global source, linear LDS dest,
// swizzled ds_read), setprio around MFMA clusters, XCD-chunked block map.
// 69 uniform K-tiles: 64 from X/W, 5 tail tiles from A2/B2t (K2=320 padded).
__global__ __launch_bounds__(512, 2) void gemm_fused(
    const bf16_t* __restrict__ X, const bf16_t* __restrict__ W,
    const bf16_t* __restrict__ A2, const bf16_t* __restrict__ B2t,
    float* __restrict__ out) {
  __shared__ __align__(16) bf16_t As[2][256 * 64];   // 64 KiB
  __shared__ __align__(16) bf16_t Bs[2][256 * 64];   // 64 KiB
  const int tid = threadIdx.x;
  const int w = tid >> 6, l = tid & 63;
  // T1: chunked XCD swizzle — 256 blocks, 32 contiguous tiles per XCD
  const int nb = (blockIdx.x & 7) * 32 + (blockIdx.x >> 3);
  const int mBase = (nb >> 4) * 256, nBase = (nb & 15) * 256;
  const int wm = w >> 2, wn = w & 3;                 // 2M x 4N wave grid
  const int lr = l & 15, lk = (l >> 4) * 8;

  // swizzled ds_read byte offsets (row stride 128B; swz = (row&7)<<4)
  int aoff[8], boff[4];
#pragma unroll
  for (int mi = 0; mi < 8; ++mi) {
    const int row = wm * 128 + mi * 16 + lr;
    aoff[mi] = row * 128 + ((lk * 2) ^ ((row & 7) << 4));
  }
#pragma unroll
  for (int ni = 0; ni < 4; ++ni) {
    const int row = wn * 64 + ni * 16 + lr;
    boff[ni] = row * 128 + ((lk * 2) ^ ((row & 7) << 4));
  }

  f32x4_t acc[8][4];
#pragma unroll
  for (int i = 0; i < 8; ++i)
#pragma unroll
    for (int j = 0; j < 4; ++j) { f32x4_t z = {0.f, 0.f, 0.f, 0.f}; acc[i][j] = z; }

  // stage one 256x64 A-tile + B-tile into buf (linear LDS dest, swizzled
  // global source column so swizzled ds_read recovers the right element).
  // 8 gload_lds per thread per tile -> vmcnt tracks 8 per tile per wave.
  auto stage = [&](int kt, int buf) {
    const int rsub = w * 8 + (l >> 3);
    const int scol = ((l & 7) ^ ((l >> 3) & 7)) << 3;
    bf16_t* lA = &As[buf][w * 512];
    bf16_t* lB = &Bs[buf][w * 512];
    if (kt < 64) {
      const bf16_t* gA = X + (size_t)(mBase + rsub) * IN_DIM + kt * 64 + scol;
      const bf16_t* gB = W + (size_t)(nBase + rsub) * IN_DIM + kt * 64 + scol;
#pragma unroll
      for (int i = 0; i < 4; ++i) {
        gload_lds16(gA + (size_t)(i * 64) * IN_DIM, lA + i * 4096);
        gload_lds16(gB + (size_t)(i * 64) * IN_DIM, lB + i * 4096);
      }
    } else {
      const int koff = (kt - 64) * 64;
      const bf16_t* gA = A2 + (size_t)(mBase + rsub) * K2 + koff + scol;
      const bf16_t* gB = B2t + (size_t)(nBase + rsub) * K2 + koff + scol;
#pragma unroll
      for (int i = 0; i < 4; ++i) {
        gload_lds16(gA + (size_t)(i * 64) * K2, lA + i * 4096);
        gload_lds16(gB + (size_t)(i * 64) * K2, lB + i * 4096);
      }
    }
  };

  stage(0, 0);
  stage(1, 1);
  // wait own tile-0 loads (8 newest = tile 1's), then all-waves barrier
  asm volatile("s_waitcnt vmcnt(8)\n\ts_barrier" ::: "memory");

  int cur = 0;
  for (int kt = 0; kt < NT_TILES; ++kt) {
    const char* Ab = (const char*)&As[cur][0];
    const char* Bb = (const char*)&Bs[cur][0];
    bf16x8_t a0[8], p0[4], a1[8], p1[4];
    // k-step 0 fragments
#pragma unroll
    for (int mi = 0; mi < 8; ++mi) a0[mi] = *(const bf16x8_t*)(Ab + aoff[mi]);
#pragma unroll
    for (int ni = 0; ni < 4; ++ni) p0[ni] = *(const bf16x8_t*)(Bb + boff[ni]);
    __builtin_amdgcn_s_setprio(1);
#pragma unroll
    for (int mi = 0; mi < 8; ++mi)
#pragma unroll
      for (int ni = 0; ni < 4; ++ni)
        acc[mi][ni] = __builtin_amdgcn_mfma_f32_16x16x32_bf16(a0[mi], p0[ni], acc[mi][ni], 0, 0, 0);
    __builtin_amdgcn_s_setprio(0);
    // k-step 1 fragments (byte addr = ks0 addr ^ 64 under the swizzle)
#pragma unroll
    for (int mi = 0; mi < 8; ++mi) a1[mi] = *(const bf16x8_t*)(Ab + (aoff[mi] ^ 64));
#pragma unroll
    for (int ni = 0; ni < 4; ++ni) p1[ni] = *(const bf16x8_t*)(Bb + (boff[ni] ^ 64));
    // barrier 1: all waves done reading buf[cur] -> safe to re-stage it
    asm volatile("s_waitcnt lgkmcnt(0)\n\ts_barrier" ::: "memory");
    stage(kt + 2 < NT_TILES ? kt + 2 : NT_TILES - 1, cur);
    __builtin_amdgcn_s_setprio(1);
#pragma unroll
    for (int mi = 0; mi < 8; ++mi)
#pragma unroll
      for (int ni = 0; ni < 4; ++ni)
        acc[mi][ni] = __builtin_amdgcn_mfma_f32_16x16x32_bf16(a1[mi], p1[ni], acc[mi][ni], 0, 0, 0);
    __builtin_amdgcn_s_setprio(0);
    // barrier 2: counted vmcnt — tile kt+1 landed, kt+2's 8 stay in flight
    asm volatile("s_waitcnt vmcnt(8)\n\ts_barrier" ::: "memory");
    cur ^= 1;
  }
  asm volatile("s_waitcnt vmcnt(0)" ::: "memory");  // drain clamped prefetch

  const int row0 = (l >> 4) * 4;  // C/D: col = lane&15, row = (lane>>4)*4 + r
#pragma unroll
  for (int mi = 0; mi < 8; ++mi) {
    const int m = mBase + wm * 128 + mi * 16 + row0;
#pragma unroll
    for (int ni = 0; ni < 4; ++ni) {
      const int n = nBase + wn * 64 + ni * 16 + lr;
      f32x4_t v = acc[mi][ni];
#pragma unroll
      for (int r = 0; r < 4; ++r) out[(size_t)(m + r) * OUT_DIM + n] = v[r];
    }
  }
}

extern "C" void kernel_launch(void* const* d_in, const int* in_sizes, int n_in,
                              void* d_out, int out_size, void* d_ws, size_t ws_size,
                              hipStream_t stream) {
  const float* x   = (const float*)d_in[0];
  const float* gw  = (const float*)d_in[1];
  const float* sw  = (const float*)d_in[2];
  const float* sb  = (const float*)d_in[3];
  const float* u   = (const float*)d_in[4];
  const float* svh = (const float*)d_in[5];
  const float* eb  = (const float*)d_in[6];
  float* out = (float*)d_out;

  char* ws = (char*)d_ws;
  size_t off = 0;
  auto carve = [&](size_t bytes) {
    void* p = ws + off;
    off = (off + bytes + 255) & ~(size_t)255;
    return p;
  };
  bf16_t* Xbf = (bf16_t*)carve(XSZ * 2);
  bf16_t* Wbf = (bf16_t*)carve(WSZ * 2);
  bf16_t* Vbf = (bf16_t*)carve(VSZ * 2);
  float*  part = (float*)carve((size_t)KSPLIT * T_TOK * 64 * 4);
  float*  hkp  = (float*)carve((size_t)HSPLIT * T_TOK * 256 * 4);
  bf16_t* A2   = (bf16_t*)carve((size_t)T_TOK * K2 * 2);
  bf16_t* B2t  = (bf16_t*)carve((size_t)OUT_DIM * K2 * 2);
  (void)ws_size; (void)in_sizes; (void)n_in; (void)out_size;

  // K1: gate partials + B2t + all casts in one launch
  k1_prep<<<(int)(NGATE + NB2T + NCAST), 256, 0, stream>>>(
      x, gw, sw, svh, u, eb, sb, Xbf, Wbf, Vbf, B2t, part);

  // K2: hk split-K partials (bf16 MFMA), 512 blocks
  svh_gemm<<<dim3(2, 32, HSPLIT), 256, 0, stream>>>(Xbf, Vbf, hkp);

  // K3: router weights + A2 assembly, 256 blocks
  router_a2<<<T_TOK / 16, 256, 0, stream>>>(part, hkp, A2);

  // K4: one fused 256^2 deep-pipelined GEMM -> d_out
  gemm_fused<<<dim3(256), 512, 0, stream>>>(Xbf, Wbf, A2, B2t, out);
}

// Round 3
// 349.361 us; speedup vs baseline: 1.2316x; 1.0001x over previous
//
#include <hip/hip_runtime.h>
#include <cstdint>
#include <cstddef>

typedef __bf16 bf16_t;
typedef __attribute__((ext_vector_type(4))) __bf16 bf16x4_t;
typedef __attribute__((ext_vector_type(8))) __bf16 bf16x8_t;
typedef __attribute__((ext_vector_type(4))) float f32x4_t;

#define T_TOK   4096
#define IN_DIM  4096
#define OUT_DIM 4096
#define K2      320    // 256 hk cols | 8 w cols | 1 shared_b col | 55 zero pad (5x BK=64 tiles)
#define KSPLIT  8      // gate split-K (512 wide)
#define HSPLIT  8      // svh-gemm split-K (K=512 each) -> 512 blocks
#define NT_TILES 69    // 64 main K-tiles (4096/64) + 5 tail tiles (320/64)

#define XSZ ((size_t)T_TOK * IN_DIM)
#define WSZ ((size_t)OUT_DIM * IN_DIM)
#define VSZ ((size_t)256 * IN_DIM)
#define NGATE  512                           // gate blocks (64 tgrp x KSPLIT)
#define NB2T_B 512                           // b2t blocks (8 o each)
#define NCAST  ((XSZ + WSZ + VSZ) / 16384)   // 2112 fat cast blocks (16K floats)

__device__ __forceinline__ void gload_lds16(const bf16_t* g, bf16_t* l) {
  __builtin_amdgcn_global_load_lds(
      (__attribute__((address_space(1))) void*)(g),
      (__attribute__((address_space(3))) void*)(l), 16, 0, 0);
}

// ===== K1: uber-kernel — gate partials | B2t build | fp32->bf16 casts ======
// gate LDS 17.4 KB (K-chunk 32) so cast blocks co-reside 8/CU.
__global__ __launch_bounds__(256) void k1_prep(const float* __restrict__ x,
                                               const float* __restrict__ gw,
                                               const float* __restrict__ sw,
                                               const float* __restrict__ svh,
                                               const float* __restrict__ u,
                                               const float* __restrict__ eb,
                                               const float* __restrict__ sb,
                                               bf16_t* __restrict__ Xbf,
                                               bf16_t* __restrict__ Wbf,
                                               bf16_t* __restrict__ Vbf,
                                               bf16_t* __restrict__ B2t,
                                               float* __restrict__ part) {
  __shared__ __align__(16) float GateLds[32 * 68 * 2];  // 17.4 KB
  const int bid = blockIdx.x;
  const int tid = threadIdx.x;

  if (bid < NGATE) {
    // ---- fp32 gate matmul partials (router precision) ----
    float* Xs = GateLds;            // [kk][t] stride 68
    float* Gs = GateLds + 32 * 68;  // [kk][r]
    const int tbase = (bid & 63) * 64;
    const int kbase = (bid >> 6) * (IN_DIM / KSPLIT);
    const int tg = tid & 15;
    const int rg = tid >> 4;
    float acc[4][4] = {{0.f}};

    for (int cc = 0; cc < (IN_DIM / KSPLIT) / 32; ++cc) {  // 16 chunks of K=32
      const int kc = kbase + cc * 32;
      __syncthreads();
#pragma unroll
      for (int j = 0; j < 2; ++j) {
        const int f = tid * 8 + j * 4;          // [0, 2048)
        const int tt = f >> 5, k4 = f & 31;
        float4 xv = *(const float4*)&x[(size_t)(tbase + tt) * IN_DIM + kc + k4];
        Xs[(k4 + 0) * 68 + tt] = xv.x; Xs[(k4 + 1) * 68 + tt] = xv.y;
        Xs[(k4 + 2) * 68 + tt] = xv.z; Xs[(k4 + 3) * 68 + tt] = xv.w;
        float4 gv = *(const float4*)&gw[(size_t)tt * IN_DIM + kc + k4];
        Gs[(k4 + 0) * 68 + tt] = gv.x; Gs[(k4 + 1) * 68 + tt] = gv.y;
        Gs[(k4 + 2) * 68 + tt] = gv.z; Gs[(k4 + 3) * 68 + tt] = gv.w;
      }
      __syncthreads();
#pragma unroll 4
      for (int kk = 0; kk < 32; ++kk) {
        float4 xv = *(const float4*)&Xs[kk * 68 + tg * 4];
        float4 gv = *(const float4*)&Gs[kk * 68 + rg * 4];
        float xa[4] = {xv.x, xv.y, xv.z, xv.w};
        float ga[4] = {gv.x, gv.y, gv.z, gv.w};
#pragma unroll
        for (int i = 0; i < 4; ++i)
#pragma unroll
          for (int j = 0; j < 4; ++j) acc[i][j] = fmaf(xa[i], ga[j], acc[i][j]);
      }
    }
    const int ks = bid >> 6;
#pragma unroll
    for (int i = 0; i < 4; ++i) {
      float4 o4 = make_float4(acc[i][0], acc[i][1], acc[i][2], acc[i][3]);
      *(float4*)&part[((size_t)ks * T_TOK + tbase + tg * 4 + i) * 64 + rg * 4] = o4;
    }
  } else if (bid < NGATE + NB2T_B) {
    // ---- B2t[o][c] = u[e][o][k] | eb[e][o] | sb[o] | 0  (8 o per block) ----
    const int o = (bid - NGATE) * 8 + (tid >> 5);
    for (int c = tid & 31; c < K2; c += 32) {
      float v;
      if (c < 256)       v = u[((size_t)(c >> 5) * OUT_DIM + o) * 32 + (c & 31)];
      else if (c < 264)  v = eb[(size_t)(c - 256) * OUT_DIM + o];
      else if (c == 264) v = sb[o];
      else               v = 0.f;
      B2t[(size_t)o * K2 + c] = (__bf16)v;
    }
  } else {
    // ---- casts: x->Xbf, sw->Wbf, svh->Vbf (16384 floats/block, 16 rounds) --
    size_t base = (size_t)(bid - NGATE - NB2T_B) * 16384;
    const float* src; bf16_t* dst; size_t i0;
    if (base < XSZ)            { src = x;   dst = Xbf; i0 = base; }
    else if (base < XSZ + WSZ) { src = sw;  dst = Wbf; i0 = base - XSZ; }
    else                       { src = svh; dst = Vbf; i0 = base - XSZ - WSZ; }
#pragma unroll
    for (int j = 0; j < 16; ++j) {
      size_t i = i0 + (size_t)j * 1024 + (size_t)tid * 4;
      float4 v = *(const float4*)(src + i);
      bf16x4_t o;
      o[0] = (__bf16)v.x; o[1] = (__bf16)v.y; o[2] = (__bf16)v.z; o[3] = (__bf16)v.w;
      *(bf16x4_t*)(dst + i) = o;
    }
  }
}

// ===== K2: svh split-K GEMM: hkp[s][t][n] = sum_{k in s} Xbf[t,k]Vbf[n,k] ===
__global__ __launch_bounds__(256) void svh_gemm(const bf16_t* __restrict__ X,
                                                const bf16_t* __restrict__ V,
                                                float* __restrict__ hkp) {
  __shared__ __align__(16) bf16_t As[128 * 32];
  __shared__ __align__(16) bf16_t Bs[128 * 32];
  const int tid = threadIdx.x;
  const int wave = tid >> 6, lane = tid & 63;
  const int mBase = blockIdx.y * 128, nBase = blockIdx.x * 128;
  const int koff = blockIdx.z * (IN_DIM / HSPLIT);
  const int wm = wave >> 1, wn = wave & 1;
  const int lr = lane & 15, lk = (lane >> 4) * 8;
  const int arow = lane >> 2, acol = (lane & 3) * 8;

  f32x4_t acc[4][4];
#pragma unroll
  for (int i = 0; i < 4; ++i)
#pragma unroll
    for (int j = 0; j < 4; ++j) { f32x4_t z = {0.f, 0.f, 0.f, 0.f}; acc[i][j] = z; }

  const bf16_t* gA = X + (size_t)(mBase + wave * 32 + arow) * IN_DIM + koff + acol;
  const bf16_t* gB = V + (size_t)(nBase + wave * 32 + arow) * IN_DIM + koff + acol;
  bf16_t* lA = &As[(wave * 32) * 32];
  bf16_t* lB = &Bs[(wave * 32) * 32];

  for (int k0 = 0; k0 < IN_DIM / HSPLIT; k0 += 32) {
    gload_lds16(gA + k0, lA);
    gload_lds16(gA + k0 + (size_t)16 * IN_DIM, lA + 16 * 32);
    gload_lds16(gB + k0, lB);
    gload_lds16(gB + k0 + (size_t)16 * IN_DIM, lB + 16 * 32);
    __syncthreads();
    bf16x8_t a[4], b[4];
#pragma unroll
    for (int mi = 0; mi < 4; ++mi)
      a[mi] = *(const bf16x8_t*)&As[(wm * 64 + mi * 16 + lr) * 32 + lk];
#pragma unroll
    for (int ni = 0; ni < 4; ++ni)
      b[ni] = *(const bf16x8_t*)&Bs[(wn * 64 + ni * 16 + lr) * 32 + lk];
#pragma unroll
    for (int mi = 0; mi < 4; ++mi)
#pragma unroll
      for (int ni = 0; ni < 4; ++ni)
        acc[mi][ni] = __builtin_amdgcn_mfma_f32_16x16x32_bf16(a[mi], b[ni], acc[mi][ni], 0, 0, 0);
    __syncthreads();
  }

  const int row0 = (lane >> 4) * 4;
  float* hs = hkp + (size_t)blockIdx.z * T_TOK * 256;
#pragma unroll
  for (int mi = 0; mi < 4; ++mi) {
    const int m = mBase + wm * 64 + mi * 16 + row0;
#pragma unroll
    for (int ni = 0; ni < 4; ++ni) {
      const int n = nBase + wn * 64 + ni * 16 + lr;
      f32x4_t v = acc[mi][ni];
#pragma unroll
      for (int r = 0; r < 4; ++r) hs[(size_t)(m + r) * 256 + n] = v[r];
    }
  }
}

// ===== K3: router + A2, wide (256 blocks x 16 tokens, cooperative) ==========
__global__ __launch_bounds__(256) void router_a2(const float* __restrict__ part,
                                                 const float* __restrict__ hkp,
                                                 bf16_t* __restrict__ A2) {
  __shared__ float pl[16 * 16];
  __shared__ float wls[16 * 8];
  const int tid = threadIdx.x;
  const int tbase = blockIdx.x * 16;

  {
    const int tt = tid >> 4, rq = tid & 15;
    const int t = tbase + tt;
    float4 s = make_float4(0.f, 0.f, 0.f, 0.f);
#pragma unroll
    for (int ks = 0; ks < KSPLIT; ++ks) {
      float4 p = *(const float4*)&part[((size_t)ks * T_TOK + t) * 64 + rq * 4];
      s.x += p.x; s.y += p.y; s.z += p.z; s.w += p.w;
    }
    pl[tt * 16 + rq] = s.x * s.x + s.y * s.y + s.z * s.z + s.w * s.w;
  }
  __syncthreads();
  if (tid < 16) {
    const int tt = tid;
    float rl[8];
#pragma unroll
    for (int e = 0; e < 8; ++e)
      rl[e] = sqrtf(pl[tt * 16 + e * 2] + pl[tt * 16 + e * 2 + 1]);
    int e1 = 0; float v1 = rl[0];
#pragma unroll
    for (int e = 1; e < 8; ++e) if (rl[e] > v1) { v1 = rl[e]; e1 = e; }
    int e2 = -1; float v2 = -1e30f;
#pragma unroll
    for (int e = 0; e < 8; ++e) if (e != e1 && rl[e] > v2) { v2 = rl[e]; e2 = e; }
    float w1 = 1.f / (1.f + expf(v2 - v1));
#pragma unroll
    for (int e = 0; e < 8; ++e) wls[tt * 8 + e] = 0.f;
    wls[tt * 8 + e1] = w1; wls[tt * 8 + e2] = 1.f - w1;
  }
  __syncthreads();
  for (int tt = 0; tt < 16; ++tt) {
    const int t = tbase + tt;
    for (int c = tid; c < K2; c += 256) {
      float v;
      if (c < 256) {
        float s = 0.f;
#pragma unroll
        for (int ks = 0; ks < HSPLIT; ++ks)
          s += hkp[((size_t)ks * T_TOK + t) * 256 + c];
        v = s * wls[tt * 8 + (c >> 5)];
      } else if (c < 264) v = wls[tt * 8 + (c - 256)];
      else if (c == 264)  v = 1.0f;
      else                v = 0.f;
      A2[(size_t)t * K2 + c] = (__bf16)v;
    }
  }
}

// ===== K4: fused GEMM: out = Xbf.Wbf^T (K=4096) + A2.B2t^T (K=320) =========
// 256x256 tile, BK=64, 8 waves (2Mx4N), 4-phase-per-tile schedule. Overwrite
// safety proof: every stage is issued >=1 barrier AFTER a barrier that all
// readers of the target buffer reached only after completing lgkmcnt(0) on
// their reads. P4 therefore waits lgkmcnt(0) BEFORE its barrier (cost ~0:
// the vmcnt(4) global-latency wait dominates), making P1's A-stage safe.
// Single counted s_waitcnt vmcnt(4) per tile — never drains in the loop.
__global__ __launch_bounds__(512, 2) void gemm_fused(
    const bf16_t* __restrict__ X, const bf16_t* __restrict__ W,
    const bf16_t* __restrict__ A2, const bf16_t* __restrict__ B2t,
    float* __restrict__ out) {
  __shared__ __align__(16) bf16_t As[2][256 * 64];   // 64 KiB
  __shared__ __align__(16) bf16_t Bs[2][256 * 64];   // 64 KiB
  const int tid = threadIdx.x;
  const int w = tid >> 6, l = tid & 63;
  // T1: chunked XCD swizzle — 256 blocks, 32 contiguous tiles per XCD
  const int nb = (blockIdx.x & 7) * 32 + (blockIdx.x >> 3);
  const int mBase = (nb >> 4) * 256, nBase = (nb & 15) * 256;
  const int wm = w >> 2, wn = w & 3;                 // 2M x 4N wave grid
  const int lr = l & 15, lk = (l >> 4) * 8;

  // swizzled ds_read byte offsets (row stride 128B; swz = (row&7)<<4)
  int aoff[8], boff[4];
#pragma unroll
  for (int mi = 0; mi < 8; ++mi) {
    const int row = wm * 128 + mi * 16 + lr;
    aoff[mi] = row * 128 + ((lk * 2) ^ ((row & 7) << 4));
  }
#pragma unroll
  for (int ni = 0; ni < 4; ++ni) {
    const int row = wn * 64 + ni * 16 + lr;
    boff[ni] = row * 128 + ((lk * 2) ^ ((row & 7) << 4));
  }

  f32x4_t acc[8][4];
#pragma unroll
  for (int i = 0; i < 8; ++i)
#pragma unroll
    for (int j = 0; j < 4; ++j) { f32x4_t z = {0.f, 0.f, 0.f, 0.f}; acc[i][j] = z; }

  // stage one 128-row half of A or B for tile kt into buf (2 gload_lds/thread)
  const int srow = w * 16 + (l >> 3);                    // rows covered per instr
  const int scol = ((l & 7) ^ ((l >> 3) & 7)) << 3;      // pre-swizzled source col
  auto stage_half = [&](int kt, int buf, int half, int mat) {
    bf16_t* lds = (mat ? &Bs[buf][0] : &As[buf][0]) + (half * 128 + w * 16) * 64;
    const int grow = (mat ? nBase : mBase) + half * 128 + srow;
    if (kt < 64) {
      const bf16_t* g = (mat ? W : X) + (size_t)grow * IN_DIM + kt * 64 + scol;
      gload_lds16(g, lds);
      gload_lds16(g + (size_t)8 * IN_DIM, lds + 8 * 64);
    } else {
      const bf16_t* g = (mat ? B2t : A2) + (size_t)grow * K2 + (kt - 64) * 64 + scol;
      gload_lds16(g, lds);
      gload_lds16(g + (size_t)8 * K2, lds + 8 * 64);
    }
  };

  // prologue: tile0 full -> buf0 (8 loads), B(1) -> buf1 (4 loads)
  stage_half(0, 0, 0, 0); stage_half(0, 0, 1, 0);
  stage_half(0, 0, 0, 1); stage_half(0, 0, 1, 1);
  stage_half(1, 1, 0, 1); stage_half(1, 1, 1, 1);
  asm volatile("s_waitcnt vmcnt(4)" ::: "memory");   // tile0's 8 landed
  asm volatile("s_barrier" ::: "memory");

#define MFMA16(M0, M1)                                                          \
  __builtin_amdgcn_s_setprio(1);                                               \
  _Pragma("unroll")                                                            \
  for (int ni = 0; ni < 4; ++ni) {                                             \
    acc[M0][ni] = __builtin_amdgcn_mfma_f32_16x16x32_bf16(a0, b0[ni], acc[M0][ni], 0, 0, 0); \
    acc[M0][ni] = __builtin_amdgcn_mfma_f32_16x16x32_bf16(a1, b1[ni], acc[M0][ni], 0, 0, 0); \
    acc[M1][ni] = __builtin_amdgcn_mfma_f32_16x16x32_bf16(a2, b0[ni], acc[M1][ni], 0, 0, 0); \
    acc[M1][ni] = __builtin_amdgcn_mfma_f32_16x16x32_bf16(a3, b1[ni], acc[M1][ni], 0, 0, 0); \
  }                                                                            \
  __builtin_amdgcn_s_setprio(0);

  int cur = 0;
  for (int kt = 0; kt < NT_TILES; ++kt) {
    const char* Ab = (const char*)&As[cur][0];
    const char* Bb = (const char*)&Bs[cur][0];
    const int nkt1 = kt + 1 < NT_TILES ? kt + 1 : NT_TILES - 1;
    const int nkt2 = kt + 2 < NT_TILES ? kt + 2 : NT_TILES - 1;
    bf16x8_t b0[4], b1[4], a0, a1, a2, a3;

    // ---- phase 1: all B frags + a[0,1]; stage A-half0(kt+1) -> buf^1
    //      (safe: all readers of As[buf^1] completed lgkm before P4's barrier)
#pragma unroll
    for (int ni = 0; ni < 4; ++ni) {
      b0[ni] = *(const bf16x8_t*)(Bb + boff[ni]);
      b1[ni] = *(const bf16x8_t*)(Bb + (boff[ni] ^ 64));
    }
    a0 = *(const bf16x8_t*)(Ab + aoff[0]);
    a1 = *(const bf16x8_t*)(Ab + (aoff[0] ^ 64));
    a2 = *(const bf16x8_t*)(Ab + aoff[1]);
    a3 = *(const bf16x8_t*)(Ab + (aoff[1] ^ 64));
    stage_half(nkt1, cur ^ 1, 0, 0);
    asm volatile("s_barrier" ::: "memory");
    asm volatile("s_waitcnt lgkmcnt(0)" ::: "memory");
    MFMA16(0, 1)

    // ---- phase 2: a[2,3]; stage A-half1(kt+1) -> buf^1
    a0 = *(const bf16x8_t*)(Ab + aoff[2]);
    a1 = *(const bf16x8_t*)(Ab + (aoff[2] ^ 64));
    a2 = *(const bf16x8_t*)(Ab + aoff[3]);
    a3 = *(const bf16x8_t*)(Ab + (aoff[3] ^ 64));
    stage_half(nkt1, cur ^ 1, 1, 0);
    asm volatile("s_barrier" ::: "memory");
    asm volatile("s_waitcnt lgkmcnt(0)" ::: "memory");
    MFMA16(2, 3)

    // ---- phase 3: a[4,5]; stage B-half0(kt+2) -> buf (B(kt) read in P1,
    //      readers' lgkm done before P2's barrier)
    a0 = *(const bf16x8_t*)(Ab + aoff[4]);
    a1 = *(const bf16x8_t*)(Ab + (aoff[4] ^ 64));
    a2 = *(const bf16x8_t*)(Ab + aoff[5]);
    a3 = *(const bf16x8_t*)(Ab + (aoff[5] ^ 64));
    stage_half(nkt2, cur, 0, 1);
    asm volatile("s_barrier" ::: "memory");
    asm volatile("s_waitcnt lgkmcnt(0)" ::: "memory");
    MFMA16(4, 5)

    // ---- phase 4: a[6,7]; stage B-half1(kt+2) -> buf; counted vmcnt +
    //      PRE-barrier lgkm(0) so every wave's reads of both buffers are
    //      complete before anyone passes this barrier (closes P1-stage race)
    a0 = *(const bf16x8_t*)(Ab + aoff[6]);
    a1 = *(const bf16x8_t*)(Ab + (aoff[6] ^ 64));
    a2 = *(const bf16x8_t*)(Ab + aoff[7]);
    a3 = *(const bf16x8_t*)(Ab + (aoff[7] ^ 64));
    stage_half(nkt2, cur, 1, 1);
    // vmcnt(4): P1/P2's A(kt+1) landed + prior B(kt+1); B(kt+2) stays in flight
    asm volatile("s_waitcnt vmcnt(4) lgkmcnt(0)" ::: "memory");
    asm volatile("s_barrier" ::: "memory");
    MFMA16(6, 7)

    cur ^= 1;
  }
  asm volatile("s_waitcnt vmcnt(0)" ::: "memory");  // drain clamped prefetch
#undef MFMA16

  const int row0 = (l >> 4) * 4;  // C/D: col = lane&15, row = (lane>>4)*4 + r
#pragma unroll
  for (int mi = 0; mi < 8; ++mi) {
    const int m = mBase + wm * 128 + mi * 16 + row0;
#pragma unroll
    for (int ni = 0; ni < 4; ++ni) {
      const int n = nBase + wn * 64 + ni * 16 + lr;
      f32x4_t v = acc[mi][ni];
#pragma unroll
      for (int r = 0; r < 4; ++r) out[(size_t)(m + r) * OUT_DIM + n] = v[r];
    }
  }
}

extern "C" void kernel_launch(void* const* d_in, const int* in_sizes, int n_in,
                              void* d_out, int out_size, void* d_ws, size_t ws_size,
                              hipStream_t stream) {
  const float* x   = (const float*)d_in[0];
  const float* gw  = (const float*)d_in[1];
  const float* sw  = (const float*)d_in[2];
  const float* sb  = (const float*)d_in[3];
  const float* u   = (const float*)d_in[4];
  const float* svh = (const float*)d_in[5];
  const float* eb  = (const float*)d_in[6];
  float* out = (float*)d_out;

  char* ws = (char*)d_ws;
  size_t off = 0;
  auto carve = [&](size_t bytes) {
    void* p = ws + off;
    off = (off + bytes + 255) & ~(size_t)255;
    return p;
  };
  bf16_t* Xbf = (bf16_t*)carve(XSZ * 2);
  bf16_t* Wbf = (bf16_t*)carve(WSZ * 2);
  bf16_t* Vbf = (bf16_t*)carve(VSZ * 2);
  float*  part = (float*)carve((size_t)KSPLIT * T_TOK * 64 * 4);
  float*  hkp  = (float*)carve((size_t)HSPLIT * T_TOK * 256 * 4);
  bf16_t* A2   = (bf16_t*)carve((size_t)T_TOK * K2 * 2);
  bf16_t* B2t  = (bf16_t*)carve((size_t)OUT_DIM * K2 * 2);
  (void)ws_size; (void)in_sizes; (void)n_in; (void)out_size;

  // K1: gate partials + B2t + all casts in one launch
  k1_prep<<<(int)(NGATE + NB2T_B + NCAST), 256, 0, stream>>>(
      x, gw, sw, svh, u, eb, sb, Xbf, Wbf, Vbf, B2t, part);

  // K2: hk split-K partials (bf16 MFMA), 512 blocks
  svh_gemm<<<dim3(2, 32, HSPLIT), 256, 0, stream>>>(Xbf, Vbf, hkp);

  // K3: router weights + A2 assembly, 256 blocks
  router_a2<<<T_TOK / 16, 256, 0, stream>>>(part, hkp, A2);

  // K4: one fused 256^2 4-phase-per-tile GEMM -> d_out
  gemm_fused<<<dim3(256), 512, 0, stream>>>(Xbf, Wbf, A2, B2t, out);
}